// Round 5
// baseline (118.451 us; speedup 1.0000x reference)
//
#include <hip/hip_runtime.h>

// Radix2ModGroup: per 8-element group, quantize to int magnitude (SF=0.05,
// |q|<=255), keep the 12 largest-exponent power-of-two terms across the
// group's 64 (element,bit) candidates (ties -> lowest element index),
// reconstruct.
//
// One thread per group (two contiguous float4 loads). Branchless selection:
// pack the 8 magnitudes into a uint64, 8x8 bit-transpose so bit position
// 8*e + (7-i) encodes candidate (exponent e, element i) -> bit position is a
// strict priority (exponent major, low index minor), so "top-12 terms" ==
// "top-12 set bits" (branchless rank-select).
//
// Division x/0.05f is bit-exact via the Markstein sequence: RN(1/0.05f) is
// exactly 20.0f, so q0 = x*20; r = fma(-0.05f,q0,x); q = fma(r,20,q0) is the
// correctly rounded IEEE quotient for all normal-range inputs (3 ops instead
// of the ~10-op div_scale/div_fixup expansion). Verified by absmax == 0.

constexpr float SF = 0.05f;
constexpr float RCP = 20.0f;   // RN(1 / 0.05f) == 20.0f exactly
constexpr int NUM_EXPS = 12;

typedef float vfloat4 __attribute__((ext_vector_type(4)));  // native vector:
                                                            // nontemporal
                                                            // builtins reject
                                                            // HIP_vector_type

__device__ __forceinline__ unsigned long long transpose8x8(unsigned long long x) {
  // bit(8r+c) <-> bit(8c+r)  (Hacker's Delight 8x8 bit-matrix transpose)
  unsigned long long t;
  t = (x ^ (x >> 7)) & 0x00AA00AA00AA00AAull; x ^= t ^ (t << 7);
  t = (x ^ (x >> 14)) & 0x0000CCCC0000CCCCull; x ^= t ^ (t << 14);
  t = (x ^ (x >> 28)) & 0x00000000F0F0F0F0ull; x ^= t ^ (t << 28);
  return x;
}

__global__ __launch_bounds__(256) void radix2_mod_group_kernel(
    const vfloat4* __restrict__ xv, vfloat4* __restrict__ ov) {
  int g = blockIdx.x * blockDim.x + threadIdx.x;  // grid divides exactly

  vfloat4 a = __builtin_nontemporal_load(&xv[2 * g]);
  vfloat4 b = __builtin_nontemporal_load(&xv[2 * g + 1]);
  float v[8] = {a.x, a.y, a.z, a.w, b.x, b.y, b.z, b.w};

  // Quantize; pack |q_i| into byte (7-i) of M.
  unsigned long long M = 0ull;
#pragma unroll
  for (int i = 0; i < 8; ++i) {
    float q0 = v[i] * RCP;
    float r0 = __builtin_fmaf(-SF, q0, v[i]);
    float q = __builtin_fmaf(r0, RCP, q0);     // == v[i] / 0.05f, exact
    float r = rintf(q);                        // RTNE == jnp.round
    r = fminf(fmaxf(r, -255.0f), 255.0f);
    int qi = (int)r;
    unsigned mi = (unsigned)(qi < 0 ? -qi : qi);
    M |= (unsigned long long)mi << (8 * (7 - i));
  }

  // w bit (8e + (7-i)) = bit e of mag_i. Position = selection priority.
  unsigned long long w = transpose8x8(M);

  // Drop the jj = max(P-12, 0) lowest-priority set bits.
  int P = __popcll(w);
  int jj = P > NUM_EXPS ? P - NUM_EXPS : 0;

  // Branchless rank-select: pos = index of the (jj+1)-th set bit from LSB.
  unsigned long long xx = w;
  int pos = 0;
  int c;
  c = __popcll(xx & 0xffffffffull);
  { int s = (jj >= c); pos += s << 5; jj -= s ? c : 0; xx = s ? (xx >> 32) : xx; }
  c = __popc((unsigned)xx & 0xffffu);
  { int s = (jj >= c); pos += s << 4; jj -= s ? c : 0; xx = s ? (xx >> 16) : xx; }
  c = __popc((unsigned)xx & 0xffu);
  { int s = (jj >= c); pos += s << 3; jj -= s ? c : 0; xx = s ? (xx >> 8) : xx; }
  c = __popc((unsigned)xx & 0xfu);
  { int s = (jj >= c); pos += s << 2; jj -= s ? c : 0; xx = s ? (xx >> 4) : xx; }
  c = __popc((unsigned)xx & 0x3u);
  { int s = (jj >= c); pos += s << 1; jj -= s ? c : 0; xx = s ? (xx >> 2) : xx; }
  c = (int)((unsigned)xx & 1u);
  { int s = (jj >= c); pos += s; }

  unsigned long long keep = w & (~0ull << pos);

  // Transpose back: byte (7-i) of Kt = kept magnitude of element i.
  unsigned long long Kt = transpose8x8(keep);

  vfloat4 o0, o1;
#pragma unroll
  for (int i = 0; i < 8; ++i) {
    unsigned mi = (unsigned)(Kt >> (8 * (7 - i))) & 0xffu;
    // sign of q == sign of x whenever mag != 0; mag==0 -> +/-0 == 0.
    float f = copysignf((float)mi * SF, v[i]);
    if (i < 4) o0[i] = f; else o1[i - 4] = f;
  }

  __builtin_nontemporal_store(o0, &ov[2 * g]);
  __builtin_nontemporal_store(o1, &ov[2 * g + 1]);
}

extern "C" void kernel_launch(void* const* d_in, const int* in_sizes, int n_in,
                              void* d_out, int out_size, void* d_ws, size_t ws_size,
                              hipStream_t stream) {
  const float* x = (const float*)d_in[0];
  float* out = (float*)d_out;
  int n = in_sizes[0];
  int ngroups = n / 8;            // 2,097,152 for 4096x4096
  int block = 256;
  int grid = ngroups / block;     // divides exactly; no tail guard needed
  radix2_mod_group_kernel<<<grid, block, 0, stream>>>(
      (const vfloat4*)x, (vfloat4*)out);
}

// Round 6
// 111.598 us; speedup vs baseline: 1.0614x; 1.0614x over previous
//
#include <hip/hip_runtime.h>

// Radix2ModGroup: per 8-element group, quantize to int magnitude (SF=0.05,
// |q|<=255), keep the 12 largest-exponent power-of-two terms across the
// group's 64 (element,bit) candidates (ties -> lowest element index),
// reconstruct.
//
// One thread per group (two contiguous float4 loads/stores — measured fastest
// memory path; nontemporal hints measured SLOWER on gfx950, do not re-add).
// Branchless selection: pack the 8 magnitudes into a uint64, 8x8
// bit-transpose so bit position 8*e + (7-i) encodes candidate (exponent e,
// element i) -> bit position is a strict priority (exponent major, low index
// minor), so "top-12 terms" == "top-12 set bits" (branchless rank-select).
//
// Division x/0.05f is bit-exact via the Markstein sequence: RN(1/0.05f) is
// exactly 20.0f, so q0 = x*20; r = fma(-0.05f,q0,x); q = fma(r,20,q0) is the
// correctly rounded IEEE quotient for all normal-range inputs (3 ops instead
// of the ~10-op div_scale/div_fixup expansion). Validated in R4: absmax 0.

constexpr float SF = 0.05f;
constexpr float RCP = 20.0f;   // RN(1 / 0.05f) == 20.0f exactly
constexpr int NUM_EXPS = 12;

__device__ __forceinline__ unsigned long long transpose8x8(unsigned long long x) {
  // bit(8r+c) <-> bit(8c+r)  (Hacker's Delight 8x8 bit-matrix transpose)
  unsigned long long t;
  t = (x ^ (x >> 7)) & 0x00AA00AA00AA00AAull; x ^= t ^ (t << 7);
  t = (x ^ (x >> 14)) & 0x0000CCCC0000CCCCull; x ^= t ^ (t << 14);
  t = (x ^ (x >> 28)) & 0x00000000F0F0F0F0ull; x ^= t ^ (t << 28);
  return x;
}

__global__ __launch_bounds__(256) void radix2_mod_group_kernel(
    const float4* __restrict__ xv, float4* __restrict__ ov) {
  int g = blockIdx.x * blockDim.x + threadIdx.x;  // grid divides exactly

  float4 a = xv[2 * g];
  float4 b = xv[2 * g + 1];
  float v[8] = {a.x, a.y, a.z, a.w, b.x, b.y, b.z, b.w};

  // Quantize; pack |q_i| into byte (7-i) of M.
  unsigned long long M = 0ull;
#pragma unroll
  for (int i = 0; i < 8; ++i) {
    float q0 = v[i] * RCP;
    float r0 = __builtin_fmaf(-SF, q0, v[i]);
    float q = __builtin_fmaf(r0, RCP, q0);     // == v[i] / 0.05f, exact
    float r = rintf(q);                        // RTNE == jnp.round
    r = fminf(fmaxf(r, -255.0f), 255.0f);
    int qi = (int)r;
    unsigned mi = (unsigned)(qi < 0 ? -qi : qi);
    M |= (unsigned long long)mi << (8 * (7 - i));
  }

  // w bit (8e + (7-i)) = bit e of mag_i. Position = selection priority.
  unsigned long long w = transpose8x8(M);

  // Drop the jj = max(P-12, 0) lowest-priority set bits.
  int P = __popcll(w);
  int jj = P > NUM_EXPS ? P - NUM_EXPS : 0;

  // Branchless rank-select: pos = index of the (jj+1)-th set bit from LSB.
  unsigned long long xx = w;
  int pos = 0;
  int c;
  c = __popcll(xx & 0xffffffffull);
  { int s = (jj >= c); pos += s << 5; jj -= s ? c : 0; xx = s ? (xx >> 32) : xx; }
  c = __popc((unsigned)xx & 0xffffu);
  { int s = (jj >= c); pos += s << 4; jj -= s ? c : 0; xx = s ? (xx >> 16) : xx; }
  c = __popc((unsigned)xx & 0xffu);
  { int s = (jj >= c); pos += s << 3; jj -= s ? c : 0; xx = s ? (xx >> 8) : xx; }
  c = __popc((unsigned)xx & 0xfu);
  { int s = (jj >= c); pos += s << 2; jj -= s ? c : 0; xx = s ? (xx >> 4) : xx; }
  c = __popc((unsigned)xx & 0x3u);
  { int s = (jj >= c); pos += s << 1; jj -= s ? c : 0; xx = s ? (xx >> 2) : xx; }
  c = (int)((unsigned)xx & 1u);
  { int s = (jj >= c); pos += s; }

  unsigned long long keep = w & (~0ull << pos);

  // Transpose back: byte (7-i) of Kt = kept magnitude of element i.
  unsigned long long Kt = transpose8x8(keep);

  float o[8];
#pragma unroll
  for (int i = 0; i < 8; ++i) {
    unsigned mi = (unsigned)(Kt >> (8 * (7 - i))) & 0xffu;
    // sign of q == sign of x whenever mag != 0; mag==0 -> +/-0 == 0.
    o[i] = copysignf((float)mi * SF, v[i]);
  }

  ov[2 * g] = make_float4(o[0], o[1], o[2], o[3]);
  ov[2 * g + 1] = make_float4(o[4], o[5], o[6], o[7]);
}

extern "C" void kernel_launch(void* const* d_in, const int* in_sizes, int n_in,
                              void* d_out, int out_size, void* d_ws, size_t ws_size,
                              hipStream_t stream) {
  const float* x = (const float*)d_in[0];
  float* out = (float*)d_out;
  int n = in_sizes[0];
  int ngroups = n / 8;            // 2,097,152 for 4096x4096
  int block = 256;
  int grid = ngroups / block;     // divides exactly; no tail guard needed
  radix2_mod_group_kernel<<<grid, block, 0, stream>>>(
      (const float4*)x, (float4*)out);
}